// Round 12
// baseline (219.072 us; speedup 1.0000x reference)
//
#include <hip/hip_runtime.h>
#include <stdint.h>

#define B_ 8
#define N_ 4000
#define C_ 80
#define NC_ (N_ * C_)          // 320000 candidates per image
#define KP_ 2048               // K_PRE
#define CAND_ 4096             // compaction capacity = SLOTS_*SLOTCAP_
#define SLOTS_ 32
#define SLOTCAP_ 128
#define DET_ 100
#define NW_ 32                 // u64 words per NMS row (2048 bits)
#define CLIP_ 4.135166556742356f

#define PB_ 80                 // proposals per k_scores block (round-3/10-validated)
#define IB_ (N_ / PB_)         // 50 blocks per image
#define CB_ 64                 // coarse bins ((key>>20)-960)
#define SEGB_ 64               // compact blocks per image
#define U4PT_ 5                // uint4 per thread in compact (64*256*5 >= 80000)

#define RT_ 256                // threads per rank block
#define RI_ 4                  // i-keys per thread (amortize LDS broadcast 4x)
#define RJS_ 16                // j-slices
#define RSL_ (CAND_ / RJS_)    // 256 keys per slice
#define RIB_ (CAND_ / (RT_ * RI_))  // 4 i-blocks per image
#define IBK_ (CAND_ / 256)     // 16 scatter blocks per image

typedef unsigned long long u64;

__device__ __forceinline__ void decode4(const float4 pr, const float4 d,
                                        float& x1, float& y1, float& x2, float& y2) {
  float w = pr.z - pr.x, h = pr.w - pr.y;
  float cx = pr.x + 0.5f * w, cy = pr.y + 0.5f * h;
  float dx = d.x / 10.0f, dy = d.y / 10.0f;
  float dw = fminf(d.z / 5.0f, CLIP_), dh = fminf(d.w / 5.0f, CLIP_);
  float pcx = dx * w + cx, pcy = dy * h + cy;
  float pw = expf(dw) * w, ph = expf(dh) * h;
  x1 = pcx - 0.5f * pw; y1 = pcy - 0.5f * ph;
  x2 = pcx + 0.5f * pw; y2 = pcy + 0.5f * ph;
}

// Sum the IB_ per-block coarse partials for image b (coalesced 256B rows,
// L2-hot); returns this lane's coarse-bin total for t<64.
__device__ __forceinline__ uint32_t coarse_sum(const uint32_t* __restrict__ histPart,
                                               int b, int t, uint32_t (*wsum)[CB_]) {
  int l = t & 63, wv = t >> 6;
  uint32_t v = 0;
  for (int j = wv; j < IB_; j += 4)
    v += histPart[((size_t)b * IB_ + j) * CB_ + l];
  wsum[wv][l] = v;
  __syncthreads();
  return (t < CB_) ? (wsum[0][t] + wsum[1][t] + wsum[2][t] + wsum[3][t]) : 0u;
}

// K1: FUSED softmax + keys + LDS coarse histogram -> PLAIN-STORE partials.
// PB_=80: the order-exact (bit-exact) per-proposal max/denom phase runs on
// 80 lanes instead of 16. No contended global atomics (round-6 lesson),
// no fences (round-5). Zero-stores {cnt,cand,top arrays} -> no memset.
__global__ __launch_bounds__(256) void k_scores(const float* __restrict__ logits,
                                                uint32_t* __restrict__ keys,
                                                uint32_t* __restrict__ histPart,
                                                uint4* __restrict__ zr, int zrN) {
  __shared__ float lds[PB_ * 81];      // 25.9 KB
  __shared__ float mArr[PB_], dArr[PB_];
  __shared__ uint32_t hcnt[CB_];
  int blk = blockIdx.x;                 // 0 .. B_*IB_-1
  int b = blk / IB_, lb = blk - b * IB_;
  int p0 = b * N_ + lb * PB_;           // global proposal base
  int t = threadIdx.x;
  for (int i = blk * 256 + t; i < zrN; i += B_ * IB_ * 256)
    zr[i] = make_uint4(0u, 0u, 0u, 0u);
  if (t < CB_) hcnt[t] = 0;
  const float4* src = (const float4*)(logits + (size_t)p0 * 81);
  for (int k = t; k < PB_ * 81 / 4; k += 256) ((float4*)lds)[k] = src[k];
  __syncthreads();
  if (t < PB_) {
    const float* lp = lds + t * 81;
    float m = lp[0];
    for (int i = 1; i <= C_; ++i) m = fmaxf(m, lp[i]);
    float denom = 0.f;
    for (int i = 0; i <= C_; ++i) denom += expf(lp[i] - m);
    mArr[t] = m; dArr[t] = denom;
  }
  __syncthreads();
#pragma unroll
  for (int iter = 0; iter < PB_ * C_ / 256; ++iter) {   // 25 iters
    int e = iter * 256 + t;
    int pp = e / C_, c = e - pp * C_;
    float lv = lds[pp * 81 + c + 1];
    float score = expf(lv - mArr[pp]) / dArr[pp];
    uint32_t key = 0;
    if (score > 0.01f) {
      key = __float_as_uint(score);
      atomicAdd(&hcnt[(key >> 20) - 960], 1u);          // LDS atomic only
    }
    keys[(size_t)p0 * C_ + e] = key;                    // coalesced
  }
  __syncthreads();
  if (t < CB_) histPart[((size_t)b * IB_ + lb) * CB_ + t] = hcnt[t];  // plain store
}

// K2: COARSE-ONLY threshold + compaction (validated rounds 9/10/11). thr =
// floor of the coarse bin where the top-down cumulative crosses KP_; all
// top-KP_ keys survive; the exact rank stage reproduces the reference
// top-2048 exactly.
__global__ __launch_bounds__(256) void k_compact(const uint32_t* __restrict__ keys,
                                                 const uint32_t* __restrict__ histPart,
                                                 uint32_t* __restrict__ cnt,
                                                 u64* __restrict__ cand) {
  __shared__ uint32_t wsum[4][CB_];
  __shared__ uint32_t s_thr;
  int blk = blockIdx.x;
  int b = blk / SEGB_, lb = blk - b * SEGB_;
  int t = threadIdx.x;
  uint32_t cv = coarse_sum(histPart, b, t, wsum);
  if (t < CB_) {
    uint32_t v = cv;
#pragma unroll
    for (int d = 1; d < 64; d <<= 1) {                  // wave suffix scan
      uint32_t o = __shfl_down(v, d);
      v += (t + d < 64) ? o : 0;
    }
    uint32_t nxt = __shfl_down(v, 1);
    if (t == 63) nxt = 0;
    uint32_t total = __shfl(v, 0);
    if (t == 0 && total < KP_) s_thr = 1u;              // pass all nonzero keys
    if (total >= KP_ && v >= KP_ && nxt < KP_)
      s_thr = ((uint32_t)(t + 960)) << 20;              // coarse-bin floor
  }
  __syncthreads();
  uint32_t thrb = s_thr;
  const uint4* kp4 = (const uint4*)(keys + (size_t)b * NC_);
#pragma unroll
  for (int q = 0; q < U4PT_; ++q) {
    int ti = lb * (256 * U4PT_) + q * 256 + t;
    if (ti >= NC_ / 4) break;
    uint4 k4 = kp4[ti];
    int slot = (ti >> 4) & (SLOTS_ - 1);
    uint32_t kv[4] = {k4.x, k4.y, k4.z, k4.w};
    int ns = 0;
#pragma unroll
    for (int qq = 0; qq < 4; ++qq) ns += (kv[qq] >= thrb) ? 1 : 0;
    if (ns == 0) continue;
    uint32_t pos = atomicAdd(&cnt[(b * SLOTS_ + slot) * 16], (uint32_t)ns);
    u64* seg = cand + (size_t)b * CAND_ + slot * SLOTCAP_;
    uint32_t baseIdx = (uint32_t)(ti * 4);
#pragma unroll
    for (int qq = 0; qq < 4; ++qq) {
      if (kv[qq] >= thrb) {
        if (pos < SLOTCAP_)
          seg[pos] = ((u64)kv[qq] << 32) | (uint32_t)(~(baseIdx + qq));
        ++pos;
      }
    }
  }
}

// K3: i-blocked j-split rank — plain partial writes only (no fences).
__global__ __launch_bounds__(256) void k_rank(const u64* __restrict__ cand,
                                              uint32_t* __restrict__ rankPart) {
  __shared__ u64 sh[RSL_];
  int blk = blockIdx.x;                  // b * (RIB_*RJS_) + lb * RJS_ + js
  int b = blk / (RIB_ * RJS_);
  int rem = blk - b * (RIB_ * RJS_);
  int lb = rem / RJS_, js = rem - lb * RJS_;
  int t = threadIdx.x;
  const u64* cb2 = cand + (size_t)b * CAND_;
  if (t < RSL_ / 2)
    ((ulonglong2*)sh)[t] = ((const ulonglong2*)(cb2 + js * RSL_))[t];
  int base = lb * (RT_ * RI_) + t;
  u64 ki[RI_];
#pragma unroll
  for (int q = 0; q < RI_; ++q) ki[q] = cb2[base + q * RT_];   // coalesced
  __syncthreads();
  int cnt4[RI_] = {0, 0, 0, 0};
#pragma unroll 4
  for (int j2 = 0; j2 < RSL_ / 2; ++j2) {  // 128 uniform ds_read_b128
    ulonglong2 v = ((const ulonglong2*)sh)[j2];
#pragma unroll
    for (int q = 0; q < RI_; ++q) {
      cnt4[q] += (v.x > ki[q]) ? 1 : 0;
      cnt4[q] += (v.y > ki[q]) ? 1 : 0;
    }
  }
  uint32_t* rp = rankPart + ((size_t)(b * RJS_ + js)) * CAND_ + base;
#pragma unroll
  for (int q = 0; q < RI_; ++q) rp[q * RT_] = (uint32_t)cnt4[q];  // coalesced
}

// K4: sum the RJS_ partial ranks (L2-hot) and scatter: decode + write top
// arrays at position rank. Sentinel slots keep the zero-init.
__global__ __launch_bounds__(256) void k_scatter(
    const u64* __restrict__ cand, const uint32_t* __restrict__ rankPart,
    const float* __restrict__ bbox, const float* __restrict__ props,
    float* __restrict__ topScore, int* __restrict__ topLabel,
    float* __restrict__ topBox, float* __restrict__ nmsBox) {
  int blk = blockIdx.x;                  // B_ * IBK_
  int b = blk / IBK_, lb = blk - b * IBK_;
  int t = threadIdx.x;
  int i = lb * 256 + t;
  u64 ki = cand[(size_t)b * CAND_ + i];
  if (ki == 0ull) return;
  uint32_t r = 0;
#pragma unroll
  for (int js = 0; js < RJS_; ++js)
    r += rankPart[((size_t)(b * RJS_ + js)) * CAND_ + i];
  if (r >= KP_) return;
  uint32_t sbits = (uint32_t)(ki >> 32);
  uint32_t idx = ~((uint32_t)ki);
  int n = idx / C_, c = idx % C_;
  float4 pr4 = ((const float4*)props)[(size_t)b * N_ + n];
  float4 d = ((const float4*)(bbox + ((size_t)b * N_ + n) * ((C_ + 1) * 4)))[c + 1];
  float x1, y1, x2, y2;
  decode4(pr4, d, x1, y1, x2, y2);
  float off = (float)(c + 1) * 4096.0f;
  size_t o = (size_t)b * KP_ + (size_t)r;
  topScore[o] = __uint_as_float(sbits);
  topLabel[o] = c + 1;
  ((float4*)topBox)[o] = make_float4(x1, y1, x2, y2);
  ((float4*)nmsBox)[o] = make_float4(x1 + off, y1 + off, x2 + off, y2 + off);
}

// K5 (FUSED supmat+nms, CONFLICT-FIXED): round 10 validated correctness but
// ran at 221us from a 16-way LDS bank conflict — all 16 lanes of a row-group
// read sbox[wd*64+jj] with identical jj (j mod 8 equal -> same bank quad).
// FIX: stagger jj per lane, jj=(jj0+(t&15)*5)&63. Bank math: sbox float4
// start-bank=(jj%8)*4, 5l%8 hits each residue exactly twice -> 2-way (free);
// sarea float bank=jj%32, 5l%32 distinct for 16 lanes -> conflict-free;
// srow read/write 2-way. OR-accumulation makes reordered jj bit-identical.
// Scan logic verbatim round-10 (harness-validated).
__global__ __launch_bounds__(1024) void k_nms_fused(
    const float* __restrict__ topScore, const int* __restrict__ topLabel,
    const float* __restrict__ topBox, const float* __restrict__ nmsBox,
    float* __restrict__ out) {
  __shared__ float4 sbox[KP_];          // 32 KB
  __shared__ float sarea[KP_];          //  8 KB
  __shared__ u64 srow[64][NW_];         // 16 KB
  __shared__ int s_done;
  int b = blockIdx.x, t = threadIdx.x;
  const float4* nb = (const float4*)(nmsBox + (size_t)b * KP_ * 4);
  for (int i = t; i < KP_; i += 1024) {
    float4 bx = nb[i];
    sbox[i] = bx;
    sarea[i] = fmaxf(bx.z - bx.x, 0.f) * fmaxf(bx.w - bx.y, 0.f);
  }
  if (t == 0) s_done = 0;

  const float* ts = topScore + (size_t)b * KP_;
  const int* tl = topLabel + (size_t)b * KP_;
  const float4* tb = (const float4*)(topBox + (size_t)b * KP_ * 4);

  int l = t & 63, h = l >> 5, w = l & 31;
  u64 removed = 0;
  int outCount = 0;                     // wave-uniform (wave 0)
  if (t < 64) {
    unsigned m32 = 0;
#pragma unroll
    for (int j = 0; j < 8; ++j) {
      float4 s4 = ((const float4*)ts)[l * 8 + j];
      if (!(s4.x > 0.f)) m32 |= 1u << (4 * j + 0);
      if (!(s4.y > 0.f)) m32 |= 1u << (4 * j + 1);
      if (!(s4.z > 0.f)) m32 |= 1u << (4 * j + 2);
      if (!(s4.w > 0.f)) m32 |= 1u << (4 * j + 3);
    }
    removed = ((u64)__shfl(m32, 2 * w + 1) << 32) | (u64)__shfl(m32, 2 * w);
  }
  __syncthreads();                      // sbox/sarea/s_done ready

  auto emitRow = [&](int row, bool kept) {
    if (l == (outCount & 63)) {
      float4 bx = tb[row];
      out[((size_t)b * DET_ + outCount) * 4 + 0] = bx.x;
      out[((size_t)b * DET_ + outCount) * 4 + 1] = bx.y;
      out[((size_t)b * DET_ + outCount) * 4 + 2] = bx.z;
      out[((size_t)b * DET_ + outCount) * 4 + 3] = bx.w;
      out[B_ * DET_ * 4 + (size_t)b * DET_ + outCount] = kept ? ts[row] : -1.0f;
      out[B_ * DET_ * 4 + B_ * DET_ + (size_t)b * DET_ + outCount] = (float)tl[row];
    }
    ++outCount;
  };

  // verbatim chunk-scan (round-0-proven), cur sourced from LDS srow
  auto scanChunk = [&](int c) -> bool {
    u64 cur[NW_];
#pragma unroll
    for (int k = 0; k < 32; ++k) cur[k] = srow[h * 32 + k][w];
    u64 rm = __shfl(removed, c);
    unsigned rml = (unsigned)rm, rmh = (unsigned)(rm >> 32);
#pragma unroll
    for (int k = 0; k < 32; ++k) {
      unsigned dlo = __builtin_amdgcn_readlane((unsigned)cur[k], c);
      unsigned dhi = __builtin_amdgcn_readlane((unsigned)(cur[k] >> 32), c);
      if (!((rml >> k) & 1u)) { rml |= dlo; rmh |= dhi; }
    }
#pragma unroll
    for (int k = 0; k < 32; ++k) {
      unsigned dlo = __builtin_amdgcn_readlane((unsigned)cur[k], 32 + c);
      unsigned dhi = __builtin_amdgcn_readlane((unsigned)(cur[k] >> 32), 32 + c);
      if (!((rmh >> k) & 1u)) { rml |= dlo; rmh |= dhi; }
    }
    u64 rmfull = ((u64)rmh << 32) | rml;
    u64 kb = ~rmfull;
    while (kb) {
      if (outCount >= DET_) return true;
      int k = __builtin_ctzll(kb);
      kb &= kb - 1;
      emitRow(c * 64 + k, true);
    }
    if (outCount >= DET_) return true;
    unsigned kmask = h ? ~rmh : ~rml;
    u64 acc = 0;
#pragma unroll
    for (int k = 0; k < 32; ++k)
      acc |= ((kmask >> k) & 1u) ? cur[k] : 0ull;
    acc |= __shfl_xor(acc, 32);
    removed = (l == c) ? rmfull : removed;
    if (l < 32 && l >= c) removed |= acc;
    return false;
  };

  int r = t >> 4;                       // sup-compute row 0..63
  int lane16 = t & 15;
  int w0 = lane16 << 1;                 // 2 words per thread
  for (int c = 0; c < NW_; ++c) {
    {                                   // all 1024 threads: chunk c's rows
      int i = c * 64 + r;
      float4 bi = sbox[i];
      float ai = sarea[i];
#pragma unroll
      for (int ww = 0; ww < 2; ++ww) {
        int wd = w0 + ww;
        u64 bits = 0;
        for (int jj0 = 0; jj0 < 64; ++jj0) {
          int jj = (jj0 + lane16 * 5) & 63;   // bank-stagger (see header)
          int j = wd * 64 + jj;
          if (j > i) {
            float4 bj = sbox[j];
            float ltx = fmaxf(bi.x, bj.x), lty = fmaxf(bi.y, bj.y);
            float rbx = fminf(bi.z, bj.z), rby = fminf(bi.w, bj.w);
            float iw = fmaxf(rbx - ltx, 0.f), ih = fmaxf(rby - lty, 0.f);
            float inter = iw * ih;
            float uni = ai + sarea[j] - inter;
            float iou = inter / fmaxf(uni, 1e-9f);
            if (iou > 0.5f) bits |= (1ull << jj);
          }
        }
        srow[r][wd] = bits;
      }
    }
    __syncthreads();                    // srow ready for wave 0
    if (t < 64) {
      if (scanChunk(c)) {
        if (l == 0) s_done = 1;
      }
    }
    __syncthreads();                    // scan done before srow overwrite
    if (s_done) break;
  }

  if (t < 64 && outCount < DET_) {      // backfill with suppressed rows
    for (int c2 = 0; c2 < NW_ && outCount < DET_; ++c2) {
      u64 rm = __shfl(removed, c2);
      while (rm && outCount < DET_) {
        int k = __builtin_ctzll(rm);
        rm &= rm - 1;
        emitRow(c2 * 64 + k, false);
      }
    }
  }
}

extern "C" void kernel_launch(void* const* d_in, const int* in_sizes, int n_in,
                              void* d_out, int out_size, void* d_ws, size_t ws_size,
                              hipStream_t stream) {
  const float* label_pre = (const float*)d_in[0];
  const float* bbox_pre = (const float*)d_in[1];
  const float* props = (const float*)d_in[2];
  float* out = (float*)d_out;

  char* ws = (char*)d_ws;
  size_t off = 0;
  auto alloc = [&](size_t bytes) -> void* {
    void* p = ws + off;
    off = (off + bytes + 255) & ~(size_t)255;
    return p;
  };

  uint32_t* keys = (uint32_t*)alloc((size_t)B_ * NC_ * 4);
  uint32_t* histPart = (uint32_t*)alloc((size_t)B_ * IB_ * CB_ * 4);  // written unconditionally
  // ---- single zero region, zero-stored by k_scores (all 256B multiples) ----
  size_t zero_begin = off;
  uint32_t* cnt = (uint32_t*)alloc((size_t)B_ * SLOTS_ * 16 * 4);     // 16384 B
  u64* cand = (u64*)alloc((size_t)B_ * CAND_ * 8);                    // 262144 B
  float* topScore = (float*)alloc((size_t)B_ * KP_ * 4);              // 65536 B
  int* topLabel = (int*)alloc((size_t)B_ * KP_ * 4);                  // 65536 B
  float* topBox = (float*)alloc((size_t)B_ * KP_ * 16);               // 524288 B
  float* nmsBox = (float*)alloc((size_t)B_ * KP_ * 16);               // 524288 B
  size_t zero_end = off;
  // ---- no zeroing needed ----
  uint32_t* rankPart = (uint32_t*)alloc((size_t)B_ * RJS_ * CAND_ * 4);

  if (off > ws_size) return;  // workspace too small -> fail visibly

  uint4* zr = (uint4*)(ws + zero_begin);
  int zrN = (int)((zero_end - zero_begin) / 16);

  k_scores<<<B_ * IB_, 256, 0, stream>>>(label_pre, keys, histPart, zr, zrN);
  k_compact<<<B_ * SEGB_, 256, 0, stream>>>(keys, histPart, cnt, cand);
  k_rank<<<B_ * RIB_ * RJS_, RT_, 0, stream>>>(cand, rankPart);
  k_scatter<<<B_ * IBK_, 256, 0, stream>>>(cand, rankPart, bbox_pre, props,
                                           topScore, topLabel, topBox, nmsBox);
  k_nms_fused<<<B_, 1024, 0, stream>>>(topScore, topLabel, topBox, nmsBox, out);
}

// Round 13
// 180.316 us; speedup vs baseline: 1.2149x; 1.2149x over previous
//
#include <hip/hip_runtime.h>
#include <stdint.h>

#define B_ 8
#define N_ 4000
#define C_ 80
#define NC_ (N_ * C_)          // 320000 candidates per image
#define KP_ 2048               // K_PRE
#define CAND_ 4096             // compaction capacity = SLOTS_*SLOTCAP_
#define SLOTS_ 32
#define SLOTCAP_ 128
#define DET_ 100
#define NW_ 32                 // u64 words per NMS row (2048 bits)
#define CLIP_ 4.135166556742356f

#define PB_ 80                 // proposals per k_scores block (round-3/10/11-validated)
#define IB_ (N_ / PB_)         // 50 blocks per image
#define CB_ 64                 // coarse bins ((key>>20)-960)
#define SEGB_ 64               // compact blocks per image
#define U4PT_ 5                // uint4 per thread in compact (64*256*5 >= 80000)

#define RT_ 256                // threads per rank block
#define RI_ 4                  // i-keys per thread (amortize LDS broadcast 4x)
#define RJS_ 16                // j-slices
#define RSL_ (CAND_ / RJS_)    // 256 keys per slice
#define RIB_ (CAND_ / (RT_ * RI_))  // 4 i-blocks per image
#define IBK_ (CAND_ / 256)     // 16 scatter blocks per image

typedef unsigned long long u64;

__device__ __forceinline__ void decode4(const float4 pr, const float4 d,
                                        float& x1, float& y1, float& x2, float& y2) {
  float w = pr.z - pr.x, h = pr.w - pr.y;
  float cx = pr.x + 0.5f * w, cy = pr.y + 0.5f * h;
  float dx = d.x / 10.0f, dy = d.y / 10.0f;
  float dw = fminf(d.z / 5.0f, CLIP_), dh = fminf(d.w / 5.0f, CLIP_);
  float pcx = dx * w + cx, pcy = dy * h + cy;
  float pw = expf(dw) * w, ph = expf(dh) * h;
  x1 = pcx - 0.5f * pw; y1 = pcy - 0.5f * ph;
  x2 = pcx + 0.5f * pw; y2 = pcy + 0.5f * ph;
}

// Sum the IB_ per-block coarse partials for image b (coalesced 256B rows,
// L2-hot); returns this lane's coarse-bin total for t<64.
__device__ __forceinline__ uint32_t coarse_sum(const uint32_t* __restrict__ histPart,
                                               int b, int t, uint32_t (*wsum)[CB_]) {
  int l = t & 63, wv = t >> 6;
  uint32_t v = 0;
  for (int j = wv; j < IB_; j += 4)
    v += histPart[((size_t)b * IB_ + j) * CB_ + l];
  wsum[wv][l] = v;
  __syncthreads();
  return (t < CB_) ? (wsum[0][t] + wsum[1][t] + wsum[2][t] + wsum[3][t]) : 0u;
}

// K1: FUSED softmax + keys + LDS coarse histogram -> PLAIN-STORE partials.
// PB_=80: the order-exact (bit-exact) per-proposal max/denom phase runs on
// 80 lanes instead of 16. No contended global atomics (round-6 lesson),
// no fences (round-5). Zero-stores {cnt,cand,top arrays} -> no memset.
__global__ __launch_bounds__(256) void k_scores(const float* __restrict__ logits,
                                                uint32_t* __restrict__ keys,
                                                uint32_t* __restrict__ histPart,
                                                uint4* __restrict__ zr, int zrN) {
  __shared__ float lds[PB_ * 81];      // 25.9 KB
  __shared__ float mArr[PB_], dArr[PB_];
  __shared__ uint32_t hcnt[CB_];
  int blk = blockIdx.x;                 // 0 .. B_*IB_-1
  int b = blk / IB_, lb = blk - b * IB_;
  int p0 = b * N_ + lb * PB_;           // global proposal base
  int t = threadIdx.x;
  for (int i = blk * 256 + t; i < zrN; i += B_ * IB_ * 256)
    zr[i] = make_uint4(0u, 0u, 0u, 0u);
  if (t < CB_) hcnt[t] = 0;
  const float4* src = (const float4*)(logits + (size_t)p0 * 81);
  for (int k = t; k < PB_ * 81 / 4; k += 256) ((float4*)lds)[k] = src[k];
  __syncthreads();
  if (t < PB_) {
    const float* lp = lds + t * 81;
    float m = lp[0];
    for (int i = 1; i <= C_; ++i) m = fmaxf(m, lp[i]);
    float denom = 0.f;
    for (int i = 0; i <= C_; ++i) denom += expf(lp[i] - m);
    mArr[t] = m; dArr[t] = denom;
  }
  __syncthreads();
#pragma unroll
  for (int iter = 0; iter < PB_ * C_ / 256; ++iter) {   // 25 iters
    int e = iter * 256 + t;
    int pp = e / C_, c = e - pp * C_;
    float lv = lds[pp * 81 + c + 1];
    float score = expf(lv - mArr[pp]) / dArr[pp];
    uint32_t key = 0;
    if (score > 0.01f) {
      key = __float_as_uint(score);
      atomicAdd(&hcnt[(key >> 20) - 960], 1u);          // LDS atomic only
    }
    keys[(size_t)p0 * C_ + e] = key;                    // coalesced
  }
  __syncthreads();
  if (t < CB_) histPart[((size_t)b * IB_ + lb) * CB_ + t] = hcnt[t];  // plain store
}

// K2: COARSE-ONLY threshold + compaction (validated rounds 9/10/11). thr =
// floor of the coarse bin where the top-down cumulative crosses KP_; all
// top-KP_ keys survive; the exact rank stage reproduces the reference
// top-2048 exactly.
__global__ __launch_bounds__(256) void k_compact(const uint32_t* __restrict__ keys,
                                                 const uint32_t* __restrict__ histPart,
                                                 uint32_t* __restrict__ cnt,
                                                 u64* __restrict__ cand) {
  __shared__ uint32_t wsum[4][CB_];
  __shared__ uint32_t s_thr;
  int blk = blockIdx.x;
  int b = blk / SEGB_, lb = blk - b * SEGB_;
  int t = threadIdx.x;
  uint32_t cv = coarse_sum(histPart, b, t, wsum);
  if (t < CB_) {
    uint32_t v = cv;
#pragma unroll
    for (int d = 1; d < 64; d <<= 1) {                  // wave suffix scan
      uint32_t o = __shfl_down(v, d);
      v += (t + d < 64) ? o : 0;
    }
    uint32_t nxt = __shfl_down(v, 1);
    if (t == 63) nxt = 0;
    uint32_t total = __shfl(v, 0);
    if (t == 0 && total < KP_) s_thr = 1u;              // pass all nonzero keys
    if (total >= KP_ && v >= KP_ && nxt < KP_)
      s_thr = ((uint32_t)(t + 960)) << 20;              // coarse-bin floor
  }
  __syncthreads();
  uint32_t thrb = s_thr;
  const uint4* kp4 = (const uint4*)(keys + (size_t)b * NC_);
#pragma unroll
  for (int q = 0; q < U4PT_; ++q) {
    int ti = lb * (256 * U4PT_) + q * 256 + t;
    if (ti >= NC_ / 4) break;
    uint4 k4 = kp4[ti];
    int slot = (ti >> 4) & (SLOTS_ - 1);
    uint32_t kv[4] = {k4.x, k4.y, k4.z, k4.w};
    int ns = 0;
#pragma unroll
    for (int qq = 0; qq < 4; ++qq) ns += (kv[qq] >= thrb) ? 1 : 0;
    if (ns == 0) continue;
    uint32_t pos = atomicAdd(&cnt[(b * SLOTS_ + slot) * 16], (uint32_t)ns);
    u64* seg = cand + (size_t)b * CAND_ + slot * SLOTCAP_;
    uint32_t baseIdx = (uint32_t)(ti * 4);
#pragma unroll
    for (int qq = 0; qq < 4; ++qq) {
      if (kv[qq] >= thrb) {
        if (pos < SLOTCAP_)
          seg[pos] = ((u64)kv[qq] << 32) | (uint32_t)(~(baseIdx + qq));
        ++pos;
      }
    }
  }
}

// K3: i-blocked j-split rank — plain partial writes only (no fences).
__global__ __launch_bounds__(256) void k_rank(const u64* __restrict__ cand,
                                              uint32_t* __restrict__ rankPart) {
  __shared__ u64 sh[RSL_];
  int blk = blockIdx.x;                  // b * (RIB_*RJS_) + lb * RJS_ + js
  int b = blk / (RIB_ * RJS_);
  int rem = blk - b * (RIB_ * RJS_);
  int lb = rem / RJS_, js = rem - lb * RJS_;
  int t = threadIdx.x;
  const u64* cb2 = cand + (size_t)b * CAND_;
  if (t < RSL_ / 2)
    ((ulonglong2*)sh)[t] = ((const ulonglong2*)(cb2 + js * RSL_))[t];
  int base = lb * (RT_ * RI_) + t;
  u64 ki[RI_];
#pragma unroll
  for (int q = 0; q < RI_; ++q) ki[q] = cb2[base + q * RT_];   // coalesced
  __syncthreads();
  int cnt4[RI_] = {0, 0, 0, 0};
#pragma unroll 4
  for (int j2 = 0; j2 < RSL_ / 2; ++j2) {  // 128 uniform ds_read_b128
    ulonglong2 v = ((const ulonglong2*)sh)[j2];
#pragma unroll
    for (int q = 0; q < RI_; ++q) {
      cnt4[q] += (v.x > ki[q]) ? 1 : 0;
      cnt4[q] += (v.y > ki[q]) ? 1 : 0;
    }
  }
  uint32_t* rp = rankPart + ((size_t)(b * RJS_ + js)) * CAND_ + base;
#pragma unroll
  for (int q = 0; q < RI_; ++q) rp[q * RT_] = (uint32_t)cnt4[q];  // coalesced
}

// K4: sum the RJS_ partial ranks (L2-hot) and scatter: decode + write top
// arrays at position rank. Sentinel slots keep the zero-init.
__global__ __launch_bounds__(256) void k_scatter(
    const u64* __restrict__ cand, const uint32_t* __restrict__ rankPart,
    const float* __restrict__ bbox, const float* __restrict__ props,
    float* __restrict__ topScore, int* __restrict__ topLabel,
    float* __restrict__ topBox, float* __restrict__ nmsBox) {
  int blk = blockIdx.x;                  // B_ * IBK_
  int b = blk / IBK_, lb = blk - b * IBK_;
  int t = threadIdx.x;
  int i = lb * 256 + t;
  u64 ki = cand[(size_t)b * CAND_ + i];
  if (ki == 0ull) return;
  uint32_t r = 0;
#pragma unroll
  for (int js = 0; js < RJS_; ++js)
    r += rankPart[((size_t)(b * RJS_ + js)) * CAND_ + i];
  if (r >= KP_) return;
  uint32_t sbits = (uint32_t)(ki >> 32);
  uint32_t idx = ~((uint32_t)ki);
  int n = idx / C_, c = idx % C_;
  float4 pr4 = ((const float4*)props)[(size_t)b * N_ + n];
  float4 d = ((const float4*)(bbox + ((size_t)b * N_ + n) * ((C_ + 1) * 4)))[c + 1];
  float x1, y1, x2, y2;
  decode4(pr4, d, x1, y1, x2, y2);
  float off = (float)(c + 1) * 4096.0f;
  size_t o = (size_t)b * KP_ + (size_t)r;
  topScore[o] = __uint_as_float(sbits);
  topLabel[o] = c + 1;
  ((float4*)topBox)[o] = make_float4(x1, y1, x2, y2);
  ((float4*)nmsBox)[o] = make_float4(x1 + off, y1 + off, x2 + off, y2 + off);
}

// K5: suppression bitmatrix — triangular grid (528 tiles/image). ROUND-10/12
// LESSON: in-NMS lazy fusion is serialization-bound at 8 blocks (100us even
// conflict-free); this split form spreads 4224 blocks across all CUs.
__global__ __launch_bounds__(64) void k_supmat(const float* __restrict__ nmsBox,
                                               u64* __restrict__ sup) {
  int blk = blockIdx.x;
  int b = blk / 528, r = blk - b * 528;
  int ti = 0, rem = r;
  while (rem >= 32 - ti) { rem -= 32 - ti; ++ti; }
  int tj = ti + rem;
  __shared__ float4 shj[64];
  __shared__ float sha[64];
  int l = threadIdx.x;
  const float4* boxes = (const float4*)(nmsBox + (size_t)b * KP_ * 4);
  float4 bj0 = boxes[tj * 64 + l];
  shj[l] = bj0;
  sha[l] = fmaxf(bj0.z - bj0.x, 0.f) * fmaxf(bj0.w - bj0.y, 0.f);
  int i = ti * 64 + l;
  float4 bi = boxes[i];
  float areai = fmaxf(bi.z - bi.x, 0.f) * fmaxf(bi.w - bi.y, 0.f);
  __syncthreads();
  u64 bits = 0;
  for (int jj = 0; jj < 64; ++jj) {
    int j = tj * 64 + jj;
    if (j > i) {
      float4 bj = shj[jj];
      float ltx = fmaxf(bi.x, bj.x), lty = fmaxf(bi.y, bj.y);
      float rbx = fminf(bi.z, bj.z), rby = fminf(bi.w, bj.w);
      float iw = fmaxf(rbx - ltx, 0.f), ih = fmaxf(rby - lty, 0.f);
      float inter = iw * ih;
      float uni = areai + sha[jj] - inter;
      float iou = inter / fmaxf(uni, 1e-9f);
      if (iou > 0.5f) bits |= (1ull << jj);
    }
  }
  sup[((size_t)b * KP_ + i) * NW_ + tj] = bits;
}

// K6: chunked greedy NMS with early exit + direct output emission.
__global__ __launch_bounds__(64) void k_nms_scan(const u64* __restrict__ sup,
                                                 const float* __restrict__ topScore,
                                                 const int* __restrict__ topLabel,
                                                 const float* __restrict__ topBox,
                                                 float* __restrict__ out) {
  int b = blockIdx.x, l = threadIdx.x;
  int h = l >> 5, w = l & 31;
  const u64* base = sup + (size_t)b * KP_ * NW_;
  const float* ts = topScore + (size_t)b * KP_;
  const int* tl = topLabel + (size_t)b * KP_;
  const float4* tb = (const float4*)(topBox + (size_t)b * KP_ * 4);
  unsigned m32 = 0;
#pragma unroll
  for (int j = 0; j < 8; ++j) {
    float4 s4 = ((const float4*)ts)[l * 8 + j];
    if (!(s4.x > 0.f)) m32 |= 1u << (4 * j + 0);
    if (!(s4.y > 0.f)) m32 |= 1u << (4 * j + 1);
    if (!(s4.z > 0.f)) m32 |= 1u << (4 * j + 2);
    if (!(s4.w > 0.f)) m32 |= 1u << (4 * j + 3);
  }
  u64 removed = ((u64)__shfl(m32, 2 * w + 1) << 32) | (u64)__shfl(m32, 2 * w);

  int outCount = 0;                                  // wave-uniform
  auto emitRow = [&](int row, bool kept) {
    if (l == (outCount & 63)) {
      float4 bx = tb[row];
      out[((size_t)b * DET_ + outCount) * 4 + 0] = bx.x;
      out[((size_t)b * DET_ + outCount) * 4 + 1] = bx.y;
      out[((size_t)b * DET_ + outCount) * 4 + 2] = bx.z;
      out[((size_t)b * DET_ + outCount) * 4 + 3] = bx.w;
      out[B_ * DET_ * 4 + (size_t)b * DET_ + outCount] = kept ? ts[row] : -1.0f;
      out[B_ * DET_ * 4 + B_ * DET_ + (size_t)b * DET_ + outCount] = (float)tl[row];
    }
    ++outCount;
  };

  u64 ra[32], rb[32];
  auto loadc = [&](u64* dst, int c) {
    const u64* p = base + ((size_t)c * 64 + h * 32) * NW_ + w;
#pragma unroll
    for (int k = 0; k < 32; ++k) dst[k] = p[(size_t)k * NW_];
  };
  auto chunk = [&](u64* cur, int c) -> bool {        // returns done
    u64 rm = __shfl(removed, c);
    unsigned rml = (unsigned)rm, rmh = (unsigned)(rm >> 32);
#pragma unroll
    for (int k = 0; k < 32; ++k) {
      unsigned dlo = __builtin_amdgcn_readlane((unsigned)cur[k], c);
      unsigned dhi = __builtin_amdgcn_readlane((unsigned)(cur[k] >> 32), c);
      if (!((rml >> k) & 1u)) { rml |= dlo; rmh |= dhi; }
    }
#pragma unroll
    for (int k = 0; k < 32; ++k) {
      unsigned dlo = __builtin_amdgcn_readlane((unsigned)cur[k], 32 + c);
      unsigned dhi = __builtin_amdgcn_readlane((unsigned)(cur[k] >> 32), 32 + c);
      if (!((rmh >> k) & 1u)) { rml |= dlo; rmh |= dhi; }
    }
    u64 rmfull = ((u64)rmh << 32) | rml;
    u64 kb = ~rmfull;
    while (kb) {
      if (outCount >= DET_) return true;
      int k = __builtin_ctzll(kb);
      kb &= kb - 1;
      emitRow(c * 64 + k, true);
    }
    if (outCount >= DET_) return true;
    unsigned kmask = h ? ~rmh : ~rml;
    u64 acc = 0;
#pragma unroll
    for (int k = 0; k < 32; ++k)
      acc |= ((kmask >> k) & 1u) ? cur[k] : 0ull;
    acc |= __shfl_xor(acc, 32);
    removed = (l == c) ? rmfull : removed;
    if (l < 32 && l >= c) removed |= acc;
    return false;
  };

  bool done = false;
  loadc(ra, 0);
  for (int c = 0; c < NW_ && !done; c += 2) {
    if (c + 1 < NW_) loadc(rb, c + 1);
    done = chunk(ra, c);
    if (!done) {
      if (c + 2 < NW_) loadc(ra, c + 2);
      done = chunk(rb, c + 1);
    }
  }
  if (outCount < DET_) {
    for (int c2 = 0; c2 < NW_ && outCount < DET_; ++c2) {
      u64 rm = __shfl(removed, c2);
      while (rm && outCount < DET_) {
        int k = __builtin_ctzll(rm);
        rm &= rm - 1;
        emitRow(c2 * 64 + k, false);
      }
    }
  }
}

extern "C" void kernel_launch(void* const* d_in, const int* in_sizes, int n_in,
                              void* d_out, int out_size, void* d_ws, size_t ws_size,
                              hipStream_t stream) {
  const float* label_pre = (const float*)d_in[0];
  const float* bbox_pre = (const float*)d_in[1];
  const float* props = (const float*)d_in[2];
  float* out = (float*)d_out;

  char* ws = (char*)d_ws;
  size_t off = 0;
  auto alloc = [&](size_t bytes) -> void* {
    void* p = ws + off;
    off = (off + bytes + 255) & ~(size_t)255;
    return p;
  };

  uint32_t* keys = (uint32_t*)alloc((size_t)B_ * NC_ * 4);
  uint32_t* histPart = (uint32_t*)alloc((size_t)B_ * IB_ * CB_ * 4);  // written unconditionally
  // ---- single zero region, zero-stored by k_scores (all 256B multiples) ----
  size_t zero_begin = off;
  uint32_t* cnt = (uint32_t*)alloc((size_t)B_ * SLOTS_ * 16 * 4);     // 16384 B
  u64* cand = (u64*)alloc((size_t)B_ * CAND_ * 8);                    // 262144 B
  float* topScore = (float*)alloc((size_t)B_ * KP_ * 4);              // 65536 B
  int* topLabel = (int*)alloc((size_t)B_ * KP_ * 4);                  // 65536 B
  float* topBox = (float*)alloc((size_t)B_ * KP_ * 16);               // 524288 B
  float* nmsBox = (float*)alloc((size_t)B_ * KP_ * 16);               // 524288 B
  size_t zero_end = off;
  // ---- no zeroing needed ----
  u64* sup = (u64*)alloc((size_t)B_ * KP_ * NW_ * 8);
  uint32_t* rankPart = (uint32_t*)alloc((size_t)B_ * RJS_ * CAND_ * 4);

  if (off > ws_size) return;  // workspace too small -> fail visibly

  uint4* zr = (uint4*)(ws + zero_begin);
  int zrN = (int)((zero_end - zero_begin) / 16);

  k_scores<<<B_ * IB_, 256, 0, stream>>>(label_pre, keys, histPart, zr, zrN);
  k_compact<<<B_ * SEGB_, 256, 0, stream>>>(keys, histPart, cnt, cand);
  k_rank<<<B_ * RIB_ * RJS_, RT_, 0, stream>>>(cand, rankPart);
  k_scatter<<<B_ * IBK_, 256, 0, stream>>>(cand, rankPart, bbox_pre, props,
                                           topScore, topLabel, topBox, nmsBox);
  k_supmat<<<B_ * 528, 64, 0, stream>>>(nmsBox, sup);
  k_nms_scan<<<B_, 64, 0, stream>>>(sup, topScore, topLabel, topBox, out);
}